// Round 1
// baseline (4043.082 us; speedup 1.0000x reference)
//
#include <hip/hip_runtime.h>

// ---------------------------------------------------------------------------
// BiLSTM (T=784, B=512, H=200, D=1) on MI355X.
//
// Key restructurings vs reference:
//  * D=1  =>  input gates are  x[t,b]*u[row] + v[row]   with
//       u = Wih @ W_in[:,0]   (800,)
//       v = Wih @ b_in + b    (800,)
//  * mean over batch commutes with final Linear => accumulate hsum[t][400]
//    only (no (T,B,2H) tensor).
//  * batch is split across blocks: 64 blocks = 2 dirs x 32 slices of 16.
//    Recurrence per block is private => no grid sync, 1 barrier/step.
//  * recurrent matmul h @ Whh.T via v_mfma_f32_16x16x32_bf16:
//       A = Whh  (M = gates, padded 800->896 = 56 tiles, quarter-major)
//       B = h^T  (K = hidden, padded 200->224 = 7 k-tiles, N = 16 batch)
//    Weights pre-swizzled into A-fragment order (prep_w) so the step loop
//    streams them as perfectly coalesced 16B/lane loads from L2.
//    h stored in LDS in B-fragment order (double buffered).
//  * cell state c and all gate math in fp32; only the h*Whh product is bf16.
//
// Padding invariant: padded gate rows have zero weights and zero u,v, so
// g=0 -> sigmoid=0.5, tanh(0)=0 -> c_pad stays 0 -> h_pad stays 0, which is
// exactly what the zero-padded K region of the B-fragments requires.
// ---------------------------------------------------------------------------

typedef short short8 __attribute__((ext_vector_type(8)));
typedef float f32x4 __attribute__((ext_vector_type(4)));
typedef unsigned short ushort_t;

#define T_STEPS 784
#define BATCH   512
#define HID     200
#define HP      224   // padded hidden (both K and j)
#define JT      14    // j-tiles (HP/16)
#define KT      7     // k-tiles (HP/32)
#define MT      56    // M-tiles = 4*JT
#define BBLK    16
#define MAIN_THREADS 896  // 14 waves, wave w owns j-tile w

// ws layout (bytes)
#define WS_HSUM   0                        // 784*400*4      = 1254400
#define WS_UG     1254400                  // 2*896*4        = 7168
#define WS_VG     (1254400 + 7168)         // 2*896*4        = 7168
#define WS_WSW    (1254400 + 14336)        // 2*56*7*512*2   = 802816

__device__ __forceinline__ ushort_t f2bf(float f) {
  union { float f; unsigned u; } x; x.f = f;
  unsigned r = (x.u + 0x7FFFu + ((x.u >> 16) & 1u)) >> 16;  // RNE
  return (ushort_t)r;
}

// ---------------------------------------------------------------------------
// prep_uv: u[dir][896], v[dir][896] (padded, quarter-stride 224, zeros in pad)
// grid 14 blocks x 128 threads
// ---------------------------------------------------------------------------
__global__ void prep_uv(const float* __restrict__ Wih_f, const float* __restrict__ b_f,
                        const float* __restrict__ Wih_b, const float* __restrict__ b_b,
                        const float* __restrict__ W_in, const float* __restrict__ b_in,
                        float* __restrict__ u_g, float* __restrict__ v_g) {
  int dir = blockIdx.x / 7;
  int j = (blockIdx.x % 7) * 128 + threadIdx.x;   // 0..895
  const float* Wih = dir ? Wih_b : Wih_f;
  const float* b   = dir ? b_b   : b_f;
  int q = j / HP, jj = j % HP;
  float u = 0.f, v = 0.f;
  if (jj < HID) {
    int row = q * HID + jj;
    const float* wr = Wih + (size_t)row * HID;
    for (int k = 0; k < HID; ++k) {
      u = fmaf(wr[k], W_in[k], u);
      v = fmaf(wr[k], b_in[k], v);
    }
    v += b[row];
  }
  u_g[dir * 896 + j] = u;
  v_g[dir * 896 + j] = v;
}

// ---------------------------------------------------------------------------
// prep_w: swizzle Whh (800,200) f32 -> bf16 A-fragments
//   w_sw[((dir*56+mt)*7+kt)*512 + lane*8 + e]
//   A-frag (16x16x32): lane l -> m = l&15, k = (l>>4)*8 + e
//   mt = q*14 + jt  =>  gate row = q*200 + jt*16 + m   (0 if out of range)
// grid 784 blocks x 64 threads
// ---------------------------------------------------------------------------
__global__ void prep_w(const float* __restrict__ Whh_f, const float* __restrict__ Whh_b,
                       ushort_t* __restrict__ w_sw) {
  int bid  = blockIdx.x;           // = (dir*56+mt)*7+kt
  int lane = threadIdx.x;
  int dir = bid / (MT * KT);
  int rem = bid % (MT * KT);
  int mt = rem / KT, kt = rem % KT;
  int q = mt / JT, jt = mt % JT;
  const float* W = dir ? Whh_b : Whh_f;
  int j = jt * 16 + (lane & 15);
  int row = q * HID + j;
  short8 v8;
#pragma unroll
  for (int e = 0; e < 8; ++e) {
    int k = kt * 32 + (lane >> 4) * 8 + e;
    float v = (j < HID && k < HID) ? W[(size_t)row * HID + k] : 0.f;
    v8[e] = (short)f2bf(v);
  }
  *(short8*)(w_sw + (size_t)bid * 512 + (size_t)lane * 8) = v8;
}

// ---------------------------------------------------------------------------
// main scan: 64 blocks (dir = bid&1, slice = bid>>1), 896 threads = 14 waves.
// Wave w owns j-tile w (16 hidden units, all 4 gate quarters for them).
// ---------------------------------------------------------------------------
__global__ __launch_bounds__(MAIN_THREADS, 4) void lstm_main(
    const float* __restrict__ x, const ushort_t* __restrict__ w_sw,
    const float* __restrict__ u_g, const float* __restrict__ v_g,
    float* __restrict__ hsum) {
  __shared__ __align__(16) ushort_t h_lds[2][KT * 64 * 8];  // B-frag order, dbuf
  __shared__ float u_lds[896], v_lds[896];

  const int tid  = threadIdx.x;
  const int lane = tid & 63;
  const int jt   = tid >> 6;            // wave index == j-tile
  const int dir  = blockIdx.x & 1;      // 0 fwd, 1 bwd
  const int b0   = (blockIdx.x >> 1) * BBLK;
  const int bcol = lane & 15;           // batch within slice (MFMA N / C-col)
  const int krow = lane >> 4;           // 0..3

  for (int i = tid; i < 896; i += MAIN_THREADS) {
    u_lds[i] = u_g[dir * 896 + i];
    v_lds[i] = v_g[dir * 896 + i];
  }
  for (int i = tid; i < 2 * KT * 64 * 8; i += MAIN_THREADS)
    ((ushort_t*)h_lds)[i] = 0;
  __syncthreads();

  float cst[4] = {0.f, 0.f, 0.f, 0.f};  // cell state: j = jt*16 + krow*4 + r
  const ushort_t* wb = w_sw + (size_t)dir * MT * KT * 512 + (size_t)lane * 8;

  int cur = 0;
  for (int s = 0; s < T_STEPS; ++s) {
    const int t = dir ? (T_STEPS - 1 - s) : s;
    const float xv = x[(size_t)t * BATCH + b0 + bcol];

    // B-fragments of h(t-1) from LDS (lane-contiguous 16B)
    short8 bf[KT];
#pragma unroll
    for (int kt = 0; kt < KT; ++kt)
      bf[kt] = *(const short8*)&h_lds[cur][kt * 512 + lane * 8];

    // gates pre-activations: acc[q] = Whh[quarter q, j-tile jt] @ h
    f32x4 acc[4];
#pragma unroll
    for (int q = 0; q < 4; ++q) {
      f32x4 a = {0.f, 0.f, 0.f, 0.f};
      const ushort_t* wp = wb + (size_t)(q * JT + jt) * KT * 512;
#pragma unroll
      for (int kt = 0; kt < KT; ++kt) {
        short8 af = *(const short8*)(wp + kt * 512);
        a = __builtin_amdgcn_mfma_f32_16x16x32_bf16(af, bf[kt], a, 0, 0, 0);
      }
      acc[q] = a;
    }

    // elementwise cell update; C/D layout: col = lane&15 (batch),
    // row = (lane>>4)*4 + r (gate row within tile)
    const int jbase = jt * 16 + krow * 4;
#pragma unroll
    for (int r = 0; r < 4; ++r) {
      const int j = jbase + r;
      const float gi = acc[0][r] + fmaf(xv, u_lds[j],       v_lds[j]);
      const float gf = acc[1][r] + fmaf(xv, u_lds[224 + j], v_lds[224 + j]);
      const float gg = acc[2][r] + fmaf(xv, u_lds[448 + j], v_lds[448 + j]);
      const float go = acc[3][r] + fmaf(xv, u_lds[672 + j], v_lds[672 + j]);
      const float si = __builtin_amdgcn_rcpf(1.f + __expf(-gi));
      const float sf = __builtin_amdgcn_rcpf(1.f + __expf(-gf));
      const float so = __builtin_amdgcn_rcpf(1.f + __expf(-go));
      const float tg = fmaf(2.f, __builtin_amdgcn_rcpf(1.f + __expf(-2.f * gg)), -1.f);
      const float cn = sf * cst[r] + si * tg;
      cst[r] = cn;
      const float tc = fmaf(2.f, __builtin_amdgcn_rcpf(1.f + __expf(-2.f * cn)), -1.f);
      const float h = so * tc;

      // write h(t) into next buffer in B-frag order:
      //   k-tile = j>>5, frag lane = bcol | (((j>>3)&3)<<4), elem = j&7
      const int lp = bcol | (((j >> 3) & 3) << 4);
      h_lds[cur ^ 1][(j >> 5) * 512 + lp * 8 + (j & 7)] = f2bf(h);

      // batch-partial sum for the (mean . Linear) output path
      float vs = h;
      vs += __shfl_xor(vs, 1);
      vs += __shfl_xor(vs, 2);
      vs += __shfl_xor(vs, 4);
      vs += __shfl_xor(vs, 8);
      if (bcol == 0 && j < HID)
        atomicAdd(&hsum[(size_t)t * 400 + dir * HID + j], vs);
    }
    __syncthreads();
    cur ^= 1;
  }
}

// ---------------------------------------------------------------------------
// out[t][o] = b_fc[o] + (1/512) * sum_col hsum[t][col] * W_fc[o][col]
// grid 784 x 256
// ---------------------------------------------------------------------------
__global__ void out_proj(const float* __restrict__ hsum, const float* __restrict__ Wfc,
                         const float* __restrict__ bfc, float* __restrict__ out) {
  const int t = blockIdx.x, tid = threadIdx.x;
  float a[10] = {0.f, 0.f, 0.f, 0.f, 0.f, 0.f, 0.f, 0.f, 0.f, 0.f};
  for (int col = tid; col < 400; col += 256) {
    const float hv = hsum[(size_t)t * 400 + col] * (1.f / 512.f);
#pragma unroll
    for (int o = 0; o < 10; ++o) a[o] = fmaf(hv, Wfc[o * 400 + col], a[o]);
  }
#pragma unroll
  for (int o = 0; o < 10; ++o) {
    float v = a[o];
    for (int m = 32; m; m >>= 1) v += __shfl_xor(v, m);
    a[o] = v;
  }
  __shared__ float red[4][10];
  if ((tid & 63) == 0)
#pragma unroll
    for (int o = 0; o < 10; ++o) red[tid >> 6][o] = a[o];
  __syncthreads();
  if (tid < 10)
    out[t * 10 + tid] = bfc[tid] + red[0][tid] + red[1][tid] + red[2][tid] + red[3][tid];
}

extern "C" void kernel_launch(void* const* d_in, const int* in_sizes, int n_in,
                              void* d_out, int out_size, void* d_ws, size_t ws_size,
                              hipStream_t stream) {
  const float* x     = (const float*)d_in[0];
  const float* W_in  = (const float*)d_in[1];
  const float* b_in  = (const float*)d_in[2];
  const float* Wih_f = (const float*)d_in[3];
  const float* Whh_f = (const float*)d_in[4];
  const float* b_f   = (const float*)d_in[5];
  const float* Wih_b = (const float*)d_in[6];
  const float* Whh_b = (const float*)d_in[7];
  const float* b_b   = (const float*)d_in[8];
  const float* W_fc  = (const float*)d_in[9];
  const float* b_fc  = (const float*)d_in[10];
  float* out = (float*)d_out;

  char* ws = (char*)d_ws;
  float*    hsum = (float*)(ws + WS_HSUM);
  float*    u_g  = (float*)(ws + WS_UG);
  float*    v_g  = (float*)(ws + WS_VG);
  ushort_t* w_sw = (ushort_t*)(ws + WS_WSW);

  hipMemsetAsync(hsum, 0, (size_t)T_STEPS * 400 * sizeof(float), stream);
  prep_uv<<<14, 128, 0, stream>>>(Wih_f, b_f, Wih_b, b_b, W_in, b_in, u_g, v_g);
  prep_w<<<2 * MT * KT, 64, 0, stream>>>(Whh_f, Whh_b, w_sw);
  lstm_main<<<64, MAIN_THREADS, 0, stream>>>(x, w_sw, u_g, v_g, hsum);
  out_proj<<<T_STEPS, 256, 0, stream>>>(hsum, W_fc, b_fc, out);
}

// Round 2
// 3244.055 us; speedup vs baseline: 1.2463x; 1.2463x over previous
//
#include <hip/hip_runtime.h>

// ---------------------------------------------------------------------------
// BiLSTM (T=784, B=512, H=200, D=1) on MI355X — round 2.
//
// Round-1 lesson (rocprof): 12.3k cy/step = L2 weight re-streaming (401KB/step
// at ~56B/cy/CU) + atomic drain. Fix: weights live in VGPRs (42 tiles) + LDS
// (4 tiles) for the whole scan; hsum atomics deferred one step.
//
// M-tiling is gate-interleaved: M-row m of tile mt -> gate q = m&3,
// hidden j = mt*4 + (m>>2). So M = 800 exactly (50 tiles of 16, no pad) and
// each lane's 4 C-regs are the 4 gates (i,f,g,o) of ONE hidden unit
// (j = mt*4 + (lane>>4), batch col = lane&15).
//
// K = hidden state, padded 200 -> 224 (7 k-tiles of 32); pad rows of h stay 0.
// 8 waves / 512 threads, 2 waves/SIMD => 256-VGPR cap (launch_bounds(512,2)).
//   waves 0..5: tiles 6w..6w+5, all 6 in registers (168 VGPR)
//   waves 6,7 : tiles 36..42 / 43..49, first 5 in registers + 2 from LDS
// ---------------------------------------------------------------------------

typedef short short8 __attribute__((ext_vector_type(8)));
typedef float f32x4 __attribute__((ext_vector_type(4)));
typedef unsigned short ushort_t;

#define T_STEPS 784
#define BATCH   512
#define HID     200
#define NKT     7     // K tiles of 32 (224 padded)
#define NMT     50    // M tiles of 16 (800 rows, gate-interleaved, no pad)
#define THREADS 512   // 8 waves
#define HBUF    3584  // NKT*512 ushorts per h buffer

// ws layout (bytes)
#define WS_HSUM 0                       // 784*400*4 = 1254400
#define WS_UV   1254400                 // 2*200*8*4 = 12800
#define WS_WSW  (1254400 + 12800)       // 2*50*7*512*2 = 716800  (end 1984000)

__device__ __forceinline__ ushort_t f2bf(float f) {
  union { float f; unsigned u; } x; x.f = f;
  return (ushort_t)((x.u + 0x7FFFu + ((x.u >> 16) & 1u)) >> 16);  // RNE
}

// ---------------------------------------------------------------------------
// prep_uv: uv_g[dir][j][8] = {u_i,u_f,u_g,u_o, v_i,v_f,v_g,v_o}
//   u_q = Wih[q*200+j,:] @ W_in[:,0],  v_q = Wih[q*200+j,:] @ b_in + b[q*200+j]
// grid 2 x 256
// ---------------------------------------------------------------------------
__global__ void prep_uv(const float* __restrict__ Wih_f, const float* __restrict__ b_f,
                        const float* __restrict__ Wih_b, const float* __restrict__ b_b,
                        const float* __restrict__ W_in, const float* __restrict__ b_in,
                        float* __restrict__ uv_g) {
  const int dir = blockIdx.x, j = threadIdx.x;
  if (j >= HID) return;
  const float* Wih = dir ? Wih_b : Wih_f;
  const float* b   = dir ? b_b   : b_f;
  for (int q = 0; q < 4; ++q) {
    const int row = q * HID + j;
    const float* wr = Wih + (size_t)row * HID;
    float u = 0.f, v = 0.f;
    for (int k = 0; k < HID; ++k) {
      u = fmaf(wr[k], W_in[k], u);
      v = fmaf(wr[k], b_in[k], v);
    }
    uv_g[(size_t)dir * 1600 + j * 8 + q]     = u;
    uv_g[(size_t)dir * 1600 + j * 8 + 4 + q] = v + b[row];
  }
}

// ---------------------------------------------------------------------------
// prep_w: Whh f32 -> bf16 A-fragments, gate-interleaved M order.
//   w_sw[((dir*50+mt)*7+kt)*512 + lane*8 + e]
//   A-frag lane l: m = l&15 (-> q=m&3, j=mt*4+(m>>2)), k = kt*32+(l>>4)*8+e
// grid 700 x 64
// ---------------------------------------------------------------------------
__global__ void prep_w(const float* __restrict__ Whh_f, const float* __restrict__ Whh_b,
                       ushort_t* __restrict__ w_sw) {
  const int bid = blockIdx.x, lane = threadIdx.x;
  const int dir = bid / (NMT * NKT);
  const int rem = bid % (NMT * NKT);
  const int mt = rem / NKT, kt = rem % NKT;
  const float* W = dir ? Whh_b : Whh_f;
  const int m = lane & 15;
  const int q = m & 3;
  const int j = mt * 4 + (m >> 2);
  const int row = q * HID + j;
  short8 v8;
#pragma unroll
  for (int e = 0; e < 8; ++e) {
    const int k = kt * 32 + (lane >> 4) * 8 + e;
    const float v = (k < HID) ? W[(size_t)row * HID + k] : 0.f;
    v8[e] = (short)f2bf(v);
  }
  *(short8*)(w_sw + (size_t)bid * 512 + (size_t)lane * 8) = v8;
}

// ---------------------------------------------------------------------------
// per-cell LSTM update (one hidden unit j, one batch col), gates in a[0..3]
// ---------------------------------------------------------------------------
__device__ __forceinline__ void cell_update(const f32x4 a, const int j, const int haddr,
                                            const float xv, const float* __restrict__ uv,
                                            ushort_t* __restrict__ hnext,
                                            float& c, float& hold) {
  const f32x4 U = *(const f32x4*)&uv[j * 8];
  const f32x4 V = *(const f32x4*)&uv[j * 8 + 4];
  const float gi = a[0] + fmaf(xv, U[0], V[0]);
  const float gf = a[1] + fmaf(xv, U[1], V[1]);
  const float gg = a[2] + fmaf(xv, U[2], V[2]);
  const float go = a[3] + fmaf(xv, U[3], V[3]);
  const float L1 = 1.44269504088896340736f;  // log2(e)
  // sigmoid(f)
  const float ef = __builtin_amdgcn_exp2f(-L1 * gf);
  const float sf = __builtin_amdgcn_rcpf(1.f + ef);
  // sigmoid(i)*tanh(g) with a single rcp: (1-eg)/((1+eg)(1+ei)); gate args
  // are bounded (|g| <~ 20) so the product can't overflow.
  const float ei = __builtin_amdgcn_exp2f(-L1 * gi);
  const float eg = __builtin_amdgcn_exp2f(-2.f * L1 * gg);
  const float sitg = (1.f - eg) * __builtin_amdgcn_rcpf((1.f + eg) * (1.f + ei));
  const float cn = fmaf(sf, c, sitg);
  c = cn;
  // sigmoid(o)*tanh(c), single rcp; clamp exp arg at 83 so denominator can't
  // overflow (eo <= 2^43) and the c<-29 limit value -sigmoid(o) is exact.
  const float eo = __builtin_amdgcn_exp2f(-L1 * go);
  const float ec = __builtin_amdgcn_exp2f(fminf(-2.f * L1 * cn, 83.f));
  const float h = (1.f - ec) * __builtin_amdgcn_rcpf((1.f + ec) * (1.f + eo));
  hnext[haddr] = f2bf(h);
  // reduce over the 16 batch cols (lane bits 0..3)
  float vs = h;
  vs += __shfl_xor(vs, 1);
  vs += __shfl_xor(vs, 2);
  vs += __shfl_xor(vs, 4);
  vs += __shfl_xor(vs, 8);
  hold = vs;
}

// ---------------------------------------------------------------------------
// the 784-step scan, templated on per-wave tile split (all-static indexing)
// ---------------------------------------------------------------------------
template <int NREG, int NLDS>
__device__ __forceinline__ void scan_loop(
    const int base, const int dir, const int b0, const int lane,
    const ushort_t* __restrict__ wg, const float* __restrict__ x,
    float* __restrict__ hsum, const float* __restrict__ uv_lds,
    ushort_t* __restrict__ h_lds, const ushort_t* __restrict__ w_lds_my) {
  constexpr int NT = NREG + NLDS;
  const int bcol = lane & 15, krow = lane >> 4;

  // hoist this wave's register-resident A-fragments (persist all 784 steps)
  short8 wreg[NREG][NKT];
#pragma unroll
  for (int it = 0; it < NREG; ++it)
#pragma unroll
    for (int kt = 0; kt < NKT; ++kt)
      wreg[it][kt] =
          *(const short8*)(wg + ((size_t)((base + it) * NKT + kt)) * 512 + lane * 8);

  // per-tile lane constants
  int jj[NT], haddr[NT];
#pragma unroll
  for (int it = 0; it < NT; ++it) {
    const int j = (base + it) * 4 + krow;
    jj[it] = j;
    haddr[it] = (j >> 5) * 512 + (bcol | (((j >> 3) & 3) << 4)) * 8 + (j & 7);
  }

  float c[NT], hold[NT];
#pragma unroll
  for (int it = 0; it < NT; ++it) { c[it] = 0.f; hold[it] = 0.f; }

  const int dcol = dir * HID;
  float xv = x[(size_t)(dir ? T_STEPS - 1 : 0) * BATCH + b0 + bcol];
  int t_prev = 0, cur = 0;

  for (int s = 0; s < T_STEPS; ++s) {
    const int t = dir ? (T_STEPS - 1 - s) : s;

    // deferred hsum atomics from the previous step (latency hides under
    // this step's compute; drained by the *next* barrier)
    if (s > 0 && bcol == 0) {
#pragma unroll
      for (int it = 0; it < NT; ++it)
        atomicAdd(&hsum[(size_t)t_prev * 400 + dcol + jj[it]], hold[it]);
    }

    // prefetch next step's x
    const int sn = (s + 1 < T_STEPS) ? s + 1 : s;
    const float xv_next = x[(size_t)(dir ? T_STEPS - 1 - sn : sn) * BATCH + b0 + bcol];

    // B-fragments of h(t-1)
    short8 bf[NKT];
#pragma unroll
    for (int kt = 0; kt < NKT; ++kt)
      bf[kt] = *(const short8*)&h_lds[cur * HBUF + kt * 512 + lane * 8];

    ushort_t* hnext = h_lds + (cur ^ 1) * HBUF;

#pragma unroll
    for (int it = 0; it < NREG; ++it) {
      f32x4 a = {0.f, 0.f, 0.f, 0.f};
#pragma unroll
      for (int kt = 0; kt < NKT; ++kt)
        a = __builtin_amdgcn_mfma_f32_16x16x32_bf16(wreg[it][kt], bf[kt], a, 0, 0, 0);
      cell_update(a, jj[it], haddr[it], xv, uv_lds, hnext, c[it], hold[it]);
    }
#pragma unroll
    for (int il = 0; il < NLDS; ++il) {
      f32x4 a = {0.f, 0.f, 0.f, 0.f};
#pragma unroll
      for (int kt = 0; kt < NKT; ++kt) {
        const short8 af =
            *(const short8*)&w_lds_my[il * (NKT * 512) + kt * 512 + lane * 8];
        a = __builtin_amdgcn_mfma_f32_16x16x32_bf16(af, bf[kt], a, 0, 0, 0);
      }
      cell_update(a, jj[NREG + il], haddr[NREG + il], xv, uv_lds, hnext,
                  c[NREG + il], hold[NREG + il]);
    }

    t_prev = t;
    xv = xv_next;
    __syncthreads();
    cur ^= 1;
  }
  // flush last step's sums
  if (bcol == 0) {
#pragma unroll
    for (int it = 0; it < NT; ++it)
      atomicAdd(&hsum[(size_t)t_prev * 400 + dcol + jj[it]], hold[it]);
  }
}

// ---------------------------------------------------------------------------
// main scan kernel: 64 blocks (dir = bid&1, slice = bid>>1), 512 threads.
// ---------------------------------------------------------------------------
__global__ __launch_bounds__(THREADS, 2) void lstm_main(
    const float* __restrict__ x, const ushort_t* __restrict__ w_sw,
    const float* __restrict__ uv_g, float* __restrict__ hsum) {
  __shared__ __align__(16) ushort_t h_lds[2 * HBUF];          // 14336 B
  __shared__ __align__(16) float uv_lds[HID * 8];             //  6400 B
  __shared__ __align__(16) ushort_t w_lds[4 * NKT * 512];     // 28672 B

  const int tid = threadIdx.x;
  const int lane = tid & 63;
  const int wv = tid >> 6;
  const int dir = blockIdx.x & 1;
  const int b0 = (blockIdx.x >> 1) * 16;

  const ushort_t* wg = w_sw + (size_t)dir * NMT * NKT * 512;

  // zero both h buffers (K-pad rows must stay 0 forever)
  for (int i = tid; i < HBUF; i += THREADS) ((unsigned*)h_lds)[i] = 0;
  // stage uv
  for (int i = tid; i < HID * 8; i += THREADS) uv_lds[i] = uv_g[(size_t)dir * 1600 + i];
  // stage the 4 LDS-resident weight tiles: mt = {41,42,48,49}
  for (int i = tid; i < 4 * NKT * 64; i += THREADS) {
    const int sl = i / (NKT * 64);
    const int rem = i % (NKT * 64);
    const int mt = (sl < 2) ? (41 + sl) : (48 + sl - 2);
    *(short8*)&w_lds[i * 8] =
        *(const short8*)(wg + ((size_t)(mt * NKT) * 512) + rem * 8);
  }
  __syncthreads();

  if (wv < 6) {
    scan_loop<6, 0>(6 * wv, dir, b0, lane, wg, x, hsum, uv_lds, h_lds, w_lds);
  } else {
    // wave 6: tiles 36..40 reg + {41,42} LDS (slots 0,1)
    // wave 7: tiles 43..47 reg + {48,49} LDS (slots 2,3)
    const ushort_t* wl = w_lds + (size_t)(wv - 6) * 2 * NKT * 512;
    scan_loop<5, 2>(36 + (wv - 6) * 7, dir, b0, lane, wg, x, hsum, uv_lds, h_lds, wl);
  }
}

// ---------------------------------------------------------------------------
// out[t][o] = b_fc[o] + (1/512) * sum_col hsum[t][col] * W_fc[o][col]
// grid 784 x 256
// ---------------------------------------------------------------------------
__global__ void out_proj(const float* __restrict__ hsum, const float* __restrict__ Wfc,
                         const float* __restrict__ bfc, float* __restrict__ out) {
  const int t = blockIdx.x, tid = threadIdx.x;
  float a[10] = {0.f, 0.f, 0.f, 0.f, 0.f, 0.f, 0.f, 0.f, 0.f, 0.f};
  for (int col = tid; col < 400; col += 256) {
    const float hv = hsum[(size_t)t * 400 + col] * (1.f / 512.f);
#pragma unroll
    for (int o = 0; o < 10; ++o) a[o] = fmaf(hv, Wfc[o * 400 + col], a[o]);
  }
#pragma unroll
  for (int o = 0; o < 10; ++o) {
    float v = a[o];
    for (int m = 32; m; m >>= 1) v += __shfl_xor(v, m);
    a[o] = v;
  }
  __shared__ float red[4][10];
  if ((tid & 63) == 0)
#pragma unroll
    for (int o = 0; o < 10; ++o) red[tid >> 6][o] = a[o];
  __syncthreads();
  if (tid < 10)
    out[t * 10 + tid] = bfc[tid] + red[0][tid] + red[1][tid] + red[2][tid] + red[3][tid];
}

extern "C" void kernel_launch(void* const* d_in, const int* in_sizes, int n_in,
                              void* d_out, int out_size, void* d_ws, size_t ws_size,
                              hipStream_t stream) {
  const float* x     = (const float*)d_in[0];
  const float* W_in  = (const float*)d_in[1];
  const float* b_in  = (const float*)d_in[2];
  const float* Wih_f = (const float*)d_in[3];
  const float* Whh_f = (const float*)d_in[4];
  const float* b_f   = (const float*)d_in[5];
  const float* Wih_b = (const float*)d_in[6];
  const float* Whh_b = (const float*)d_in[7];
  const float* b_b   = (const float*)d_in[8];
  const float* W_fc  = (const float*)d_in[9];
  const float* b_fc  = (const float*)d_in[10];
  float* out = (float*)d_out;

  char* ws = (char*)d_ws;
  float*    hsum = (float*)(ws + WS_HSUM);
  float*    uv_g = (float*)(ws + WS_UV);
  ushort_t* w_sw = (ushort_t*)(ws + WS_WSW);

  hipMemsetAsync(hsum, 0, (size_t)T_STEPS * 400 * sizeof(float), stream);
  prep_uv<<<2, 256, 0, stream>>>(Wih_f, b_f, Wih_b, b_b, W_in, b_in, uv_g);
  prep_w<<<2 * NMT * NKT, 64, 0, stream>>>(Whh_f, Whh_b, w_sw);
  lstm_main<<<64, THREADS, 0, stream>>>(x, w_sw, uv_g, hsum);
  out_proj<<<T_STEPS, 256, 0, stream>>>(hsum, W_fc, b_fc, out);
}

// Round 3
// 1759.062 us; speedup vs baseline: 2.2984x; 1.8442x over previous
//
#include <hip/hip_runtime.h>

// ---------------------------------------------------------------------------
// BiLSTM (T=784, B=512, H=200, D=1) on MI355X — round 3.
//
// Round-2 lesson (rocprof): VGPR_Count=128 => compiler rematerialized the
// weight loads every step instead of keeping 168 VGPRs live; still L2-bound
// (~9900 cy/step). Fixes:
//  1) asm-pin the hoisted weight fragments ("+v") so they cannot be remat'd.
//  2) fold input path into MFMA K-pad slots (k=200..204):
//       g = Whh@h + x*U + V  ==  MFMA over K=224 with
//       B[200]=1->A=Vhi, B[201]=1->A=Vlo, B[202]=xhi->A=Uhi,
//       B[203]=xhi->A=Ulo, B[204]=xlo->A=Uhi     (error ~2^-17, free compute)
//     -> kills uv_lds + 8 fmaf/cell + their registers.
//  3) tile pairs share the kt loop -> 2 independent MFMA chains (ILP 2).
//
// Per block (dir, 16-batch slice): 50 M-tiles (gate-interleaved, M=800 exact).
// 8 waves: w0..w5 own 6 reg-tiles each; w6/w7 own 5 reg-tiles + 2 LDS-tiles.
// Peak VGPR ~ 168(wreg)+28(bf)+8(acc)+~35(misc) ~= 240 < 256 (2 waves/SIMD).
// ---------------------------------------------------------------------------

typedef short short8 __attribute__((ext_vector_type(8)));
typedef float f32x4 __attribute__((ext_vector_type(4)));
typedef unsigned short ushort_t;

#define T_STEPS 784
#define BATCH   512
#define HID     200
#define NKT     7     // K tiles of 32 (224 padded; slots 200..204 = input path)
#define NMT     50    // M tiles of 16 (800 rows, gate-interleaved)
#define THREADS 512   // 8 waves
#define HBUF    3584  // NKT*512 ushorts per h buffer

// ws layout (bytes)
#define WS_HSUM 0                       // 784*400*4 = 1254400
#define WS_UV   1254400                 // 2*200*8*4 = 12800
#define WS_WSW  (1254400 + 12800)       // 2*50*7*512*2 = 716800

__device__ __forceinline__ ushort_t f2bf(float f) {
  union { float f; unsigned u; } x; x.f = f;
  return (ushort_t)((x.u + 0x7FFFu + ((x.u >> 16) & 1u)) >> 16);  // RNE
}
__device__ __forceinline__ float bf2f(ushort_t u) {
  union { unsigned u; float f; } x; x.u = (unsigned)u << 16; return x.f;
}

// ---------------------------------------------------------------------------
// prep_uv: uv_g[dir][j][8] = {u_i,u_f,u_g,u_o, v_i,v_f,v_g,v_o}
// ---------------------------------------------------------------------------
__global__ void prep_uv(const float* __restrict__ Wih_f, const float* __restrict__ b_f,
                        const float* __restrict__ Wih_b, const float* __restrict__ b_b,
                        const float* __restrict__ W_in, const float* __restrict__ b_in,
                        float* __restrict__ uv_g) {
  const int dir = blockIdx.x, j = threadIdx.x;
  if (j >= HID) return;
  const float* Wih = dir ? Wih_b : Wih_f;
  const float* b   = dir ? b_b   : b_f;
  for (int q = 0; q < 4; ++q) {
    const int row = q * HID + j;
    const float* wr = Wih + (size_t)row * HID;
    float u = 0.f, v = 0.f;
    for (int k = 0; k < HID; ++k) {
      u = fmaf(wr[k], W_in[k], u);
      v = fmaf(wr[k], b_in[k], v);
    }
    uv_g[(size_t)dir * 1600 + j * 8 + q]     = u;
    uv_g[(size_t)dir * 1600 + j * 8 + 4 + q] = v + b[row];
  }
}

// ---------------------------------------------------------------------------
// prep_w: A-fragments. kt<6: Whh. kt==6: k=192..199 Whh; k=200..204 input path.
//   A-frag lane l: m=l&15 (q=m&3, j=mt*4+(m>>2)), k = kt*32+(l>>4)*8+e
// grid 700 x 64
// ---------------------------------------------------------------------------
__global__ void prep_w(const float* __restrict__ Whh_f, const float* __restrict__ Whh_b,
                       const float* __restrict__ uv_g, ushort_t* __restrict__ w_sw) {
  const int bid = blockIdx.x, lane = threadIdx.x;
  const int dir = bid / (NMT * NKT);
  const int rem = bid % (NMT * NKT);
  const int mt = rem / NKT, kt = rem % NKT;
  const float* W = dir ? Whh_b : Whh_f;
  const int m = lane & 15;
  const int q = m & 3;
  const int j = mt * 4 + (m >> 2);
  const int row = q * HID + j;
  const int grp = lane >> 4;
  short8 v8 = {0, 0, 0, 0, 0, 0, 0, 0};
  if (kt < 6) {
#pragma unroll
    for (int e = 0; e < 8; ++e)
      v8[e] = (short)f2bf(W[(size_t)row * HID + kt * 32 + grp * 8 + e]);
  } else if (grp == 0) {          // k = 192..199
#pragma unroll
    for (int e = 0; e < 8; ++e)
      v8[e] = (short)f2bf(W[(size_t)row * HID + 192 + e]);
  } else if (grp == 1) {          // k = 200..207: input-path slots
    const float U = uv_g[(size_t)dir * 1600 + j * 8 + q];
    const float V = uv_g[(size_t)dir * 1600 + j * 8 + 4 + q];
    const ushort_t vhi = f2bf(V), uhi = f2bf(U);
    v8[0] = (short)vhi;                    // * 1.0
    v8[1] = (short)f2bf(V - bf2f(vhi));    // * 1.0
    v8[2] = (short)uhi;                    // * xhi
    v8[3] = (short)f2bf(U - bf2f(uhi));    // * xhi
    v8[4] = (short)uhi;                    // * xlo
  }
  *(short8*)(w_sw + (size_t)bid * 512 + (size_t)lane * 8) = v8;
}

// ---------------------------------------------------------------------------
// per-cell LSTM update; gates (i,f,g,o) = a[0..3] directly (input path folded)
// ---------------------------------------------------------------------------
__device__ __forceinline__ void cell_update(const f32x4 a, const int haddr,
                                            ushort_t* __restrict__ hnext,
                                            float& c, float& hold) {
  const float L1 = 1.44269504088896340736f;  // log2(e)
  const float ef = __builtin_amdgcn_exp2f(-L1 * a[1]);
  const float sf = __builtin_amdgcn_rcpf(1.f + ef);
  const float ei = __builtin_amdgcn_exp2f(-L1 * a[0]);
  const float eg = __builtin_amdgcn_exp2f(-2.f * L1 * a[2]);
  const float sitg = (1.f - eg) * __builtin_amdgcn_rcpf((1.f + eg) * (1.f + ei));
  const float cn = fmaf(sf, c, sitg);
  c = cn;
  const float eo = __builtin_amdgcn_exp2f(-L1 * a[3]);
  const float ec = __builtin_amdgcn_exp2f(fminf(-2.f * L1 * cn, 83.f));
  const float h = (1.f - ec) * __builtin_amdgcn_rcpf((1.f + ec) * (1.f + eo));
  hnext[haddr] = f2bf(h);
  float vs = h;
  vs += __shfl_xor(vs, 1);
  vs += __shfl_xor(vs, 2);
  vs += __shfl_xor(vs, 4);
  vs += __shfl_xor(vs, 8);
  hold = vs;
}

// ---------------------------------------------------------------------------
// the 784-step scan. NREG reg-tiles at rbase.., NLDS lds-tiles at lbase..
// ---------------------------------------------------------------------------
template <int NREG, int NLDS>
__device__ __forceinline__ void scan_loop(
    const int rbase, const int lbase, const int dir, const int b0,
    const int lane, const int wv, const ushort_t* __restrict__ wg,
    const float* __restrict__ x, float* __restrict__ hsum,
    ushort_t* __restrict__ h_lds, const ushort_t* __restrict__ w_lds_my) {
  constexpr int NT = NREG + NLDS;
  const int bcol = lane & 15, krow = lane >> 4;
  const bool xw = (wv == 0) & (krow == 1);  // lanes 16..31 of wave 0 feed x slots

  // hoist + PIN this wave's register-resident A-fragments (non-remat'able)
  short8 wreg[NREG][NKT];
#pragma unroll
  for (int it = 0; it < NREG; ++it)
#pragma unroll
    for (int kt = 0; kt < NKT; ++kt)
      wreg[it][kt] =
          *(const short8*)(wg + ((size_t)((rbase + it) * NKT + kt)) * 512 + lane * 8);
#pragma unroll
  for (int it = 0; it < NREG; ++it)
#pragma unroll
    for (int kt = 0; kt < NKT; ++kt)
      asm volatile("" : "+v"(wreg[it][kt]));

  int jj[NT], haddr[NT];
#pragma unroll
  for (int i = 0; i < NT; ++i) {
    const int j = ((i < NREG) ? rbase + i : lbase + (i - NREG)) * 4 + krow;
    jj[i] = j;
    haddr[i] = (j >> 5) * 512 + (bcol | (((j >> 3) & 3) << 4)) * 8 + (j & 7);
  }

  float c[NT], hold[NT];
#pragma unroll
  for (int i = 0; i < NT; ++i) { c[i] = 0.f; hold[i] = 0.f; }

  const int dcol = dir * HID;
  int t_prev = 0, cur = 0;

  for (int s = 0; s < T_STEPS; ++s) {
    const int t = dir ? (T_STEPS - 1 - s) : s;

    // deferred hsum atomics from previous step (drained by NEXT barrier)
    if (s > 0 && bcol == 0) {
#pragma unroll
      for (int i = 0; i < NT; ++i)
        atomicAdd(&hsum[(size_t)t_prev * 400 + dcol + jj[i]], hold[i]);
    }

    // x for step s+1 (only the 16 x-writer lanes touch global x)
    const int sn = (s + 1 < T_STEPS) ? s + 1 : s;
    float xn = 0.f;
    if (xw) xn = x[(size_t)(dir ? T_STEPS - 1 - sn : sn) * BATCH + b0 + bcol];

    // B-fragments of [h(t-1); 1; x(t)]
    short8 bf[NKT];
#pragma unroll
    for (int kt = 0; kt < NKT; ++kt)
      bf[kt] = *(const short8*)&h_lds[cur * HBUF + kt * 512 + lane * 8];

    ushort_t* hnext = h_lds + (cur ^ 1) * HBUF;

    // write next step's x into hnext slots k=202..204 (e=2,3: xhi; e=4: xlo)
    if (xw) {
      const ushort_t hi = f2bf(xn);
      const ushort_t lo = f2bf(xn - bf2f(hi));
      const int sb = 6 * 512 + lane * 8;
      hnext[sb + 2] = hi;
      hnext[sb + 3] = hi;
      hnext[sb + 4] = lo;
    }

    // reg tiles in pairs (2 independent MFMA chains)
#pragma unroll
    for (int p = 0; p + 1 < NREG; p += 2) {
      f32x4 a0 = {0.f, 0.f, 0.f, 0.f}, a1 = {0.f, 0.f, 0.f, 0.f};
#pragma unroll
      for (int kt = 0; kt < NKT; ++kt) {
        a0 = __builtin_amdgcn_mfma_f32_16x16x32_bf16(wreg[p][kt],     bf[kt], a0, 0, 0, 0);
        a1 = __builtin_amdgcn_mfma_f32_16x16x32_bf16(wreg[p + 1][kt], bf[kt], a1, 0, 0, 0);
      }
      cell_update(a0, haddr[p],     hnext, c[p],     hold[p]);
      cell_update(a1, haddr[p + 1], hnext, c[p + 1], hold[p + 1]);
    }
    if constexpr (NREG & 1) {
      constexpr int p = NREG - 1;
      f32x4 a0 = {0.f, 0.f, 0.f, 0.f};
#pragma unroll
      for (int kt = 0; kt < NKT; ++kt)
        a0 = __builtin_amdgcn_mfma_f32_16x16x32_bf16(wreg[p][kt], bf[kt], a0, 0, 0, 0);
      cell_update(a0, haddr[p], hnext, c[p], hold[p]);
    }
    // LDS tiles (pair)
    if constexpr (NLDS == 2) {
      f32x4 a0 = {0.f, 0.f, 0.f, 0.f}, a1 = {0.f, 0.f, 0.f, 0.f};
#pragma unroll
      for (int kt = 0; kt < NKT; ++kt) {
        const short8 af0 = *(const short8*)&w_lds_my[(0 * NKT + kt) * 512 + lane * 8];
        const short8 af1 = *(const short8*)&w_lds_my[(1 * NKT + kt) * 512 + lane * 8];
        a0 = __builtin_amdgcn_mfma_f32_16x16x32_bf16(af0, bf[kt], a0, 0, 0, 0);
        a1 = __builtin_amdgcn_mfma_f32_16x16x32_bf16(af1, bf[kt], a1, 0, 0, 0);
      }
      cell_update(a0, haddr[NREG],     hnext, c[NREG],     hold[NREG]);
      cell_update(a1, haddr[NREG + 1], hnext, c[NREG + 1], hold[NREG + 1]);
    }

    t_prev = t;
    __syncthreads();
    cur ^= 1;
  }
  if (bcol == 0) {
#pragma unroll
    for (int i = 0; i < NT; ++i)
      atomicAdd(&hsum[(size_t)t_prev * 400 + dcol + jj[i]], hold[i]);
  }
}

// ---------------------------------------------------------------------------
// main scan kernel: 64 blocks (dir = bid&1, slice = bid>>1), 512 threads.
// ---------------------------------------------------------------------------
__global__ __launch_bounds__(THREADS, 2) void lstm_main(
    const float* __restrict__ x, const ushort_t* __restrict__ w_sw,
    float* __restrict__ hsum) {
  __shared__ __align__(16) ushort_t h_lds[2 * HBUF];        // 14336 B
  __shared__ __align__(16) ushort_t w_lds[4 * NKT * 512];   // 28672 B

  const int tid = threadIdx.x;
  const int lane = tid & 63;
  const int wv = tid >> 6;
  const int dir = blockIdx.x & 1;
  const int b0 = (blockIdx.x >> 1) * 16;

  const ushort_t* wg = w_sw + (size_t)dir * NMT * NKT * 512;

  for (int i = tid; i < HBUF; i += THREADS) ((unsigned*)h_lds)[i] = 0;
  // stage LDS weight tiles {41,42,48,49}
  for (int i = tid; i < 4 * NKT * 64; i += THREADS) {
    const int sl = i / (NKT * 64);
    const int rem = i % (NKT * 64);
    const int mt = (sl < 2) ? (41 + sl) : (48 + sl - 2);
    *(short8*)&w_lds[i * 8] =
        *(const short8*)(wg + ((size_t)(mt * NKT) * 512) + rem * 8);
  }
  __syncthreads();

  // constant-1 slots (both buffers) + x(t0) slots (buffer 0)
  if (tid < 16) {
    const int t0 = dir ? T_STEPS - 1 : 0;
    const float x0 = x[(size_t)t0 * BATCH + b0 + tid];
    const ushort_t hi = f2bf(x0);
    const ushort_t lo = f2bf(x0 - bf2f(hi));
    const int sb = 6 * 512 + (16 + tid) * 8;
    h_lds[sb + 0] = 0x3F80; h_lds[sb + 1] = 0x3F80;
    h_lds[HBUF + sb + 0] = 0x3F80; h_lds[HBUF + sb + 1] = 0x3F80;
    h_lds[sb + 2] = hi; h_lds[sb + 3] = hi; h_lds[sb + 4] = lo;
  }
  __syncthreads();

  if (wv < 6) {
    scan_loop<6, 0>(6 * wv, 0, dir, b0, lane, wv, wg, x, hsum, h_lds, w_lds);
  } else if (wv == 6) {
    scan_loop<5, 2>(36, 41, dir, b0, lane, wv, wg, x, hsum, h_lds, w_lds);
  } else {
    scan_loop<5, 2>(43, 48, dir, b0, lane, wv, wg, x, hsum, h_lds,
                    w_lds + 2 * NKT * 512);
  }
}

// ---------------------------------------------------------------------------
// out[t][o] = b_fc[o] + (1/512) * sum_col hsum[t][col] * W_fc[o][col]
// ---------------------------------------------------------------------------
__global__ void out_proj(const float* __restrict__ hsum, const float* __restrict__ Wfc,
                         const float* __restrict__ bfc, float* __restrict__ out) {
  const int t = blockIdx.x, tid = threadIdx.x;
  float a[10] = {0.f, 0.f, 0.f, 0.f, 0.f, 0.f, 0.f, 0.f, 0.f, 0.f};
  for (int col = tid; col < 400; col += 256) {
    const float hv = hsum[(size_t)t * 400 + col] * (1.f / 512.f);
#pragma unroll
    for (int o = 0; o < 10; ++o) a[o] = fmaf(hv, Wfc[o * 400 + col], a[o]);
  }
#pragma unroll
  for (int o = 0; o < 10; ++o) {
    float v = a[o];
    for (int m = 32; m; m >>= 1) v += __shfl_xor(v, m);
    a[o] = v;
  }
  __shared__ float red[4][10];
  if ((tid & 63) == 0)
#pragma unroll
    for (int o = 0; o < 10; ++o) red[tid >> 6][o] = a[o];
  __syncthreads();
  if (tid < 10)
    out[t * 10 + tid] = bfc[tid] + red[0][tid] + red[1][tid] + red[2][tid] + red[3][tid];
}

extern "C" void kernel_launch(void* const* d_in, const int* in_sizes, int n_in,
                              void* d_out, int out_size, void* d_ws, size_t ws_size,
                              hipStream_t stream) {
  const float* x     = (const float*)d_in[0];
  const float* W_in  = (const float*)d_in[1];
  const float* b_in  = (const float*)d_in[2];
  const float* Wih_f = (const float*)d_in[3];
  const float* Whh_f = (const float*)d_in[4];
  const float* b_f   = (const float*)d_in[5];
  const float* Wih_b = (const float*)d_in[6];
  const float* Whh_b = (const float*)d_in[7];
  const float* b_b   = (const float*)d_in[8];
  const float* W_fc  = (const float*)d_in[9];
  const float* b_fc  = (const float*)d_in[10];
  float* out = (float*)d_out;

  char* ws = (char*)d_ws;
  float*    hsum = (float*)(ws + WS_HSUM);
  float*    uv_g = (float*)(ws + WS_UV);
  ushort_t* w_sw = (ushort_t*)(ws + WS_WSW);

  hipMemsetAsync(hsum, 0, (size_t)T_STEPS * 400 * sizeof(float), stream);
  prep_uv<<<2, 256, 0, stream>>>(Wih_f, b_f, Wih_b, b_b, W_in, b_in, uv_g);
  prep_w<<<2 * NMT * NKT, 64, 0, stream>>>(Whh_f, Whh_b, uv_g, w_sw);
  lstm_main<<<64, THREADS, 0, stream>>>(x, w_sw, hsum);
  out_proj<<<T_STEPS, 256, 0, stream>>>(hsum, W_fc, b_fc, out);
}